// Round 7
// baseline (308.611 us; speedup 1.0000x reference)
//
#include <hip/hip_runtime.h>
#include <hip/hip_bf16.h>
#include <math.h>

typedef unsigned short u16t;
typedef __bf16 bf16x8 __attribute__((ext_vector_type(8)));
typedef float f32x4 __attribute__((ext_vector_type(4)));

#define NBATCH 64
#define NT 384
#define NC 256
#define NHID 682
#define NHIDP 704
#define NHIDR 768                   // w1p/w3p padded row count (6 x 128 n-blocks in e1)
#define NTOK (NBATCH * NT)          // 24576
#define NSLOT (2 * NTOK + 1024)     // 50176 (128-padded expert regions worst case)

// setup mega-kernel block-range boundaries (256 threads/block)
#define SB0 196                      // init tok/tokw/ctrl        (196*256 = 50176 = NSLOT)
#define SB1 (SB0 + 512)              // wqkv pack   (512*256 = 131072)
#define SB2 (SB1 + 256)              // wo cvt      (256*256 = 65536)
#define SB3 (SB2 + 6144)             // pack13      (8*768*256 = 1572864, padded rows)
#define SB4 (SB3 + 5632)             // pack2       (8*256*704)
#define SB5 (SB4 + 48)               // rope table  (384*32 = 12288)
#define SB6 (SB5 + NTOK / 4)         // rms ln1 (4 tokens/block)

static __device__ __forceinline__ float bf2f(u16t u) { return __uint_as_float(((unsigned int)u) << 16); }
static __device__ __forceinline__ u16t f2bf(float f) { return __builtin_bit_cast(u16t, __float2bfloat16(f)); }

// async global->LDS, 16B per lane; LDS dest = wave-uniform base + lane*16.
static __device__ __forceinline__ void gload16(const void* gp, void* lp) {
  __builtin_amdgcn_global_load_lds((const __attribute__((address_space(1))) void*)gp,
                                   (__attribute__((address_space(3))) void*)lp, 16, 0, 0);
}

// pipeline sync helpers: raw barrier with explicit counted waits
static __device__ __forceinline__ void pipe_barrier_full() {
  asm volatile("s_waitcnt vmcnt(0) lgkmcnt(0)" ::: "memory");
  __builtin_amdgcn_s_barrier();
  asm volatile("" ::: "memory");
}

// LDS tile layout: 16B chunks, chunk(row,g) = row*8 + (g ^ (row&7)) (XOR swizzle).

// ---------------- setup mega-kernel: init + weight packs + rope table + ln1 rms ----------------
__global__ __launch_bounds__(256) void k_setup(const float* __restrict__ wq, const float* __restrict__ wk,
                                               const float* __restrict__ wv, const float* __restrict__ wo,
                                               const float* __restrict__ w1, const float* __restrict__ w2,
                                               const float* __restrict__ w3,
                                               const float* __restrict__ x, const float* __restrict__ ln1w,
                                               int* __restrict__ tok, float* __restrict__ tokw,
                                               int* __restrict__ ctrl,
                                               u16t* __restrict__ wqkvb, u16t* __restrict__ wob,
                                               u16t* __restrict__ w1p, u16t* __restrict__ w3p,
                                               u16t* __restrict__ w2p, float* __restrict__ rtab,
                                               u16t* __restrict__ h) {
  int blk = blockIdx.x, t = threadIdx.x;
  if (blk < SB0) {
    int i = blk * 256 + t;
    tok[i] = -1; tokw[i] = 0.f;
    if (blk == 0 && t < 64) ctrl[t] = 0;
  } else if (blk < SB1) {
    int i = (blk - SB0) * 256 + t;
    int row = i >> 8, col = i & 255;
    float s = (row < 256) ? wq[(size_t)row * 256 + col]
            : (row < 384) ? wk[(size_t)(row - 256) * 256 + col]
                          : wv[(size_t)(row - 384) * 256 + col];
    wqkvb[i] = f2bf(s);
  } else if (blk < SB2) {
    int i = (blk - SB1) * 256 + t;
    wob[i] = f2bf(wo[i]);
  } else if (blk < SB3) {
    int idx = (blk - SB2) * 256 + t;
    int kcol = idx & 255; int tmp = idx >> 8; int nrow = tmp % NHIDR; int e = tmp / NHIDR;
    if (nrow < NHID) {
      size_t src = ((size_t)e * NHID + nrow) * NC + kcol;
      w1p[idx] = f2bf(w1[src]); w3p[idx] = f2bf(w3[src]);
    } else { w1p[idx] = 0; w3p[idx] = 0; }
  } else if (blk < SB4) {
    int idx = (blk - SB3) * 256 + t;
    int kcol = idx % NHIDP; int tmp = idx / NHIDP; int nrow = tmp & 255; int e = tmp >> 8;
    w2p[idx] = (kcol < NHID) ? f2bf(w2[((size_t)e * NC + nrow) * NHID + kcol]) : (u16t)0;
  } else if (blk < SB5) {
    int i = (blk - SB4) * 256 + t;   // < 12288
    int tt = i >> 5, d = i & 31;
    float ang = (float)tt * powf(10000.f, -(float)d * (1.f / 32.f));
    float s, c; sincosf(ang, &s, &c);
    ((float2*)rtab)[i] = make_float2(c, s);
  } else {
    int w = t >> 6, l = t & 63;
    int n = (blk - SB5) * 4 + w;
    const float* xr = x + (size_t)n * NC;
    float4 xa = *(const float4*)(xr + l * 4);
    float ssq = xa.x * xa.x + xa.y * xa.y + xa.z * xa.z + xa.w * xa.w;
    for (int d = 1; d < 64; d <<= 1) ssq += __shfl_xor(ssq, d, 64);
    float rs = rsqrtf(ssq * (1.f / 256.f) + 1e-6f);
    float4 wa = *(const float4*)(ln1w + l * 4);
    ushort4 o;
    o.x = f2bf(xa.x * rs * wa.x);
    o.y = f2bf(xa.y * rs * wa.y);
    o.z = f2bf(xa.z * rs * wa.z);
    o.w = f2bf(xa.w * rs * wa.w);
    *(ushort4*)(h + (size_t)n * NC + l * 4) = o;
  }
}

// ---------------- fused RMSNorm + router (fp32), 4 tokens per 256-thr block ----------------
__global__ __launch_bounds__(256) void k_rms_router(const float* __restrict__ xin,
                                                    const float* __restrict__ wg,
                                                    const float* __restrict__ rw,
                                                    u16t* __restrict__ flat,
                                                    int* __restrict__ eidx,
                                                    float* __restrict__ ew) {
  int w = threadIdx.x >> 6, l = threadIdx.x & 63;
  int n = blockIdx.x * 4 + w;
  const float* xr = xin + (size_t)n * NC;
  float4 xa = *(const float4*)(xr + l * 4);
  float ssq = xa.x * xa.x + xa.y * xa.y + xa.z * xa.z + xa.w * xa.w;
  for (int d = 1; d < 64; d <<= 1) ssq += __shfl_xor(ssq, d, 64);
  float rs = rsqrtf(ssq * (1.f / 256.f) + 1e-6f);
  float4 wa = *(const float4*)(wg + l * 4);
  float n0 = xa.x * rs * wa.x, n1 = xa.y * rs * wa.y;
  float n2 = xa.z * rs * wa.z, n3 = xa.w * rs * wa.w;
  ushort4 o; o.x = f2bf(n0); o.y = f2bf(n1); o.z = f2bf(n2); o.w = f2bf(n3);
  *(ushort4*)(flat + (size_t)n * NC + l * 4) = o;
  float acc[8];
  for (int e = 0; e < 8; e++) {
    float4 ra = *(const float4*)(rw + (size_t)e * NC + l * 4);
    acc[e] = n0 * ra.x + n1 * ra.y + n2 * ra.z + n3 * ra.w;
  }
  for (int e = 0; e < 8; e++)
    for (int d = 1; d < 64; d <<= 1) acc[e] += __shfl_xor(acc[e], d, 64);
  if (l == 0) {
    float mx = acc[0];
    for (int e = 1; e < 8; e++) mx = fmaxf(mx, acc[e]);
    float p[8], sum = 0.f;
    for (int e = 0; e < 8; e++) { p[e] = __expf(acc[e] - mx); sum += p[e]; }
    float inv = 1.f / sum;
    for (int e = 0; e < 8; e++) p[e] *= inv;
    int i0 = 0; float b0 = p[0];
    for (int e = 1; e < 8; e++) if (p[e] > b0) { b0 = p[e]; i0 = e; }
    int i1 = -1; float b1 = -1.f;
    for (int e = 0; e < 8; e++) if (e != i0 && p[e] > b1) { b1 = p[e]; i1 = e; }
    float s2 = 1.f / (b0 + b1 + 1e-9f);
    eidx[n * 2] = i0; eidx[n * 2 + 1] = i1;
    ew[n * 2] = b0 * s2; ew[n * 2 + 1] = b1 * s2;
  }
}

// ---------------- fused histogram + scan + scatter: 96 co-resident blocks ----------------
// ctrl: cnt=0..7, offs=8..16, cursor=20..27, done=32, flag=33
__global__ __launch_bounds__(256) void k_hist_scatter(const int* __restrict__ eidx, const float* __restrict__ ew,
                                                      int* __restrict__ ctrl, int* __restrict__ tok,
                                                      float* __restrict__ tokw, int* __restrict__ t2s) {
  int* cnt = ctrl; int* offs = ctrl + 8; int* cursor = ctrl + 20;
  int* done = ctrl + 32; int* flag = ctrl + 33;
  __shared__ int lh[8], lcnt[8], lbase[8];
  int tid = threadIdx.x;
  if (tid < 8) { lh[tid] = 0; lcnt[tid] = 0; }
  __syncthreads();
  int n = blockIdx.x * 256 + tid;
  int e0 = eidx[n * 2], e1 = eidx[n * 2 + 1];
  atomicAdd(&lh[e0], 1); atomicAdd(&lh[e1], 1);
  __syncthreads();
  if (tid < 8) {
    atomicAdd(&cnt[tid], lh[tid]);
    __threadfence();
  }
  __syncthreads();
  if (tid == 0) {
    int prev = atomicAdd(done, 1);
    if (prev == 95) {   // last block: all cnt updates visible
      int off = 0;
      for (int e = 0; e < 8; e++) {
        int c_ = atomicAdd(&cnt[e], 0);
        offs[e] = off;                      // plain store: consumed by LATER kernels only
        atomicExch(&cursor[e], off);        // device-scope RMW: consumed by spinners below
        off += ((c_ + 127) >> 7) << 7;
      }
      offs[8] = off;
      __threadfence();
      atomicExch(flag, 1);
    }
    while (atomicAdd(flag, 0) == 0) {}      // spin until scan complete (96 blocks co-resident)
  }
  __syncthreads();
  // scatter phase
  int p0 = atomicAdd(&lcnt[e0], 1);
  int p1 = atomicAdd(&lcnt[e1], 1);
  __syncthreads();
  if (tid < 8) lbase[tid] = atomicAdd(&cursor[tid], lcnt[tid]);
  __syncthreads();
  int g0 = lbase[e0] + p0, g1 = lbase[e1] + p1;
  tok[g0] = n; tokw[g0] = ew[n * 2];
  tok[g1] = n; tokw[g1] = ew[n * 2 + 1];
  t2s[n * 2] = g0; t2s[n * 2 + 1] = g1;
}

// ---------------- fused QKV GEMM + RoPE epilogue (2-phase pipelined) ----------------
// qkv[N][512]: cols 0-255 q (4 heads), 256-383 k (2 kv heads), 384-511 v.
// NOTE: natural dim3 grid. XCD-chunked flat grid was measured -12 us across qkv/attn/wo (R5):
// all operands are L3-resident here, so L2-locality swizzling only perturbs dispatch balance.
__global__ __launch_bounds__(256) void k_gemm_qkv(const u16t* __restrict__ A,
                                                  const u16t* __restrict__ Bw,
                                                  const float* __restrict__ rtab,
                                                  u16t* __restrict__ qkv) {
  __shared__ __align__(16) u16t sA[2][128 * 64];
  __shared__ __align__(16) u16t sB[2][128 * 64];
  int t = threadIdx.x;
  int m0 = blockIdx.y * 128, n0 = blockIdx.x * 128;
  int w = t >> 6, l = t & 63, quad = l >> 4, lq = l & 15;
  int wm = (w >> 1) * 64, wn = (w & 1) * 64;
  const u16t* aP[4]; const u16t* bP[4];
  for (int i = 0; i < 4; i++) {
    int c = i * 256 + t; int r = c >> 3; int g = (c & 7) ^ (r & 7);
    aP[i] = A + (size_t)(m0 + r) * NC + g * 8;
    bP[i] = Bw + (size_t)(n0 + r) * NC + g * 8;
  }
  auto stage = [&](int p, int k0) {
    for (int i = 0; i < 4; i++) {
      gload16(aP[i] + k0, sA[p] + (size_t)(i * 256 + t) * 8);
      gload16(bP[i] + k0, sB[p] + (size_t)(i * 256 + t) * 8);
    }
  };
  const f32x4 fz = {0.f, 0.f, 0.f, 0.f};
  f32x4 acc[4][4];
  for (int i = 0; i < 4; i++) for (int j = 0; j < 4; j++) acc[i][j] = fz;
  stage(0, 0);
  pipe_barrier_full();
  for (int kb = 0; kb < 4; kb++) {
    int p = kb & 1;
    if (kb < 3) stage(p ^ 1, (kb + 1) << 6);
    for (int kk = 0; kk < 2; kk++) {
      int gq = kk * 4 + quad;
      bf16x8 af[4], bf[4];
      for (int mi = 0; mi < 4; mi++) { int row = wm + mi * 16 + lq; af[mi] = *(const bf16x8*)(sA[p] + (row * 8 + (gq ^ (row & 7))) * 8); }
      for (int ni = 0; ni < 4; ni++) { int row = wn + ni * 16 + lq; bf[ni] = *(const bf16x8*)(sB[p] + (row * 8 + (gq ^ (row & 7))) * 8); }
      for (int mi = 0; mi < 4; mi++)
        for (int ni = 0; ni < 4; ni++)
          acc[mi][ni] = __builtin_amdgcn_mfma_f32_16x16x32_bf16(af[mi], bf[ni], acc[mi][ni], 0, 0, 0);
    }
    if (kb < 3) pipe_barrier_full();
  }
  int cb = (n0 + wn) >> 6;                // 64-col head block owned by this wave
  const float2* rt = (const float2*)rtab;
  for (int mi = 0; mi < 4; mi++)
    for (int r = 0; r < 4; r++) {
      int gm = m0 + wm + mi * 16 + quad * 4 + r;
      u16t* orow = qkv + (size_t)gm * 512 + n0 + wn;
      if (cb < 6) {                       // q or k head: rope pairs (d, d+32)
        int tt = gm % NT;
        for (int ni = 0; ni < 2; ni++) {
          int d = ni * 16 + lq;
          float2 cs = rt[tt * 32 + d];
          float x1 = acc[mi][ni][r], x2 = acc[mi][ni + 2][r];
          orow[d] = f2bf(x1 * cs.x - x2 * cs.y);
          orow[d + 32] = f2bf(x2 * cs.x + x1 * cs.y);
        }
      } else {                            // v: plain store
        for (int ni = 0; ni < 4; ni++) orow[ni * 16 + lq] = f2bf(acc[mi][ni][r]);
      }
    }
}

// ---------------- GEMM + residual: xo_f32 = y @ wo^T + x_f32 (2-phase pipelined) ----------------
__global__ __launch_bounds__(256) void k_gemm_wo(const u16t* __restrict__ A,
                                                 const u16t* __restrict__ Bw,
                                                 const float* __restrict__ xin,
                                                 float* __restrict__ xo) {
  __shared__ __align__(16) u16t sA[2][128 * 64];
  __shared__ __align__(16) u16t sB[2][128 * 64];
  int t = threadIdx.x;
  int m0 = blockIdx.y * 128, n0 = blockIdx.x * 128;
  int w = t >> 6, l = t & 63, quad = l >> 4, lq = l & 15;
  int wm = (w >> 1) * 64, wn = (w & 1) * 64;
  const u16t* aP[4]; const u16t* bP[4];
  for (int i = 0; i < 4; i++) {
    int c = i * 256 + t; int r = c >> 3; int g = (c & 7) ^ (r & 7);
    aP[i] = A + (size_t)(m0 + r) * NC + g * 8;
    bP[i] = Bw + (size_t)(n0 + r) * NC + g * 8;
  }
  auto stage = [&](int p, int k0) {
    for (int i = 0; i < 4; i++) {
      gload16(aP[i] + k0, sA[p] + (size_t)(i * 256 + t) * 8);
      gload16(bP[i] + k0, sB[p] + (size_t)(i * 256 + t) * 8);
    }
  };
  const f32x4 fz = {0.f, 0.f, 0.f, 0.f};
  f32x4 acc[4][4];
  for (int i = 0; i < 4; i++) for (int j = 0; j < 4; j++) acc[i][j] = fz;
  stage(0, 0);
  pipe_barrier_full();
  for (int kb = 0; kb < 4; kb++) {
    int p = kb & 1;
    if (kb < 3) stage(p ^ 1, (kb + 1) << 6);
    for (int kk = 0; kk < 2; kk++) {
      int gq = kk * 4 + quad;
      bf16x8 af[4], bf[4];
      for (int mi = 0; mi < 4; mi++) { int row = wm + mi * 16 + lq; af[mi] = *(const bf16x8*)(sA[p] + (row * 8 + (gq ^ (row & 7))) * 8); }
      for (int ni = 0; ni < 4; ni++) { int row = wn + ni * 16 + lq; bf[ni] = *(const bf16x8*)(sB[p] + (row * 8 + (gq ^ (row & 7))) * 8); }
      for (int mi = 0; mi < 4; mi++)
        for (int ni = 0; ni < 4; ni++)
          acc[mi][ni] = __builtin_amdgcn_mfma_f32_16x16x32_bf16(af[mi], bf[ni], acc[mi][ni], 0, 0, 0);
    }
    if (kb < 3) pipe_barrier_full();
  }
  for (int mi = 0; mi < 4; mi++)
    for (int ni = 0; ni < 4; ni++) {
      int gn = n0 + wn + ni * 16 + lq;
      for (int r = 0; r < 4; r++) {
        int gm = m0 + wm + mi * 16 + quad * 4 + r;
        xo[(size_t)gm * NC + gn] = acc[mi][ni][r] + xin[(size_t)gm * NC + gn];
      }
    }
}

// ---------------- flash attention, causal GQA (bf16), 2-phase K/V pipeline ----------------
__global__ __launch_bounds__(256) void k_attn(const u16t* __restrict__ qkv,
                                              u16t* __restrict__ y) {
  __shared__ __align__(16) u16t sK[2][64 * 64];
  __shared__ __align__(16) u16t sVT[2][64 * 64];
  __shared__ __align__(16) u16t sP[4 * 32 * 64];
  int qt = blockIdx.x, h = blockIdx.y, b = blockIdx.z;
  int kvh = h >> 1;
  int t = threadIdx.x, w = t >> 6, l = t & 63, quad = l >> 4, lq = l & 15;
  int tb = qt * 128 + w * 32;
  bf16x8 qf[2][2];
  for (int mi = 0; mi < 2; mi++)
    for (int kk = 0; kk < 2; kk++)
      qf[mi][kk] = *(const bf16x8*)(qkv + ((size_t)(b * NT + tb + mi * 16 + lq)) * 512 + h * 64 + kk * 32 + quad * 8);
  const f32x4 fz = {0.f, 0.f, 0.f, 0.f};
  f32x4 accO[2][4];
  float mrow[2][4], lrow[2][4];
  for (int mi = 0; mi < 2; mi++)
    for (int ni = 0; ni < 4; ni++) accO[mi][ni] = fz;
  for (int mi = 0; mi < 2; mi++)
    for (int r = 0; r < 4; r++) { mrow[mi][r] = -1e30f; lrow[mi][r] = 0.f; }
  u16t* myP = sP + w * 2048;
  int nkt = (qt + 1) * 2;
  ushort4 vr0[2], vr1[2];
  auto stageK = [&](int p, int kt) {
    int s0 = kt * 64;
    for (int i = 0; i < 2; i++) {
      int c = i * 256 + t; int s = c >> 3; int g = (c & 7) ^ (s & 7);
      gload16(qkv + ((size_t)(b * NT + s0 + s)) * 512 + 256 + kvh * 64 + g * 8, sK[p] + (size_t)c * 8);
    }
  };
  auto vload = [&](int kt) {                 // issue V global loads into regs (T14 issue-early)
    int s0 = kt * 64;
    for (int i = 0; i < 2; i++) {
      int pI = i * 256 + t; int s = pI & 63; int n0 = (pI >> 6) * 8;
      const u16t* vp = qkv + ((size_t)(b * NT + s0 + s)) * 512 + 384 + kvh * 64 + n0;
      vr0[i] = *(const ushort4*)vp; vr1[i] = *(const ushort4*)(vp + 4);
    }
  };
  auto vstore = [&](int p) {                 // transpose-write V into LDS (T14 write-late)
    for (int i = 0; i < 2; i++) {
      int pI = i * 256 + t; int s = pI & 63; int n0 = (pI >> 6) * 8;
      u16t vv[8] = {vr0[i].x, vr0[i].y, vr0[i].z, vr0[i].w, vr1[i].x, vr1[i].y, vr1[i].z, vr1[i].w};
      for (int j = 0; j < 8; j++) {
        int nn = n0 + j;
        sVT[p][(nn * 8 + ((s >> 3) ^ (nn & 7))) * 8 + (s & 7)] = vv[j];
      }
    }
  };
  stageK(0, 0); vload(0); vstore(0);
  pipe_barrier_full();
  for (int kt = 0; kt < nkt; kt++) {
    int p = kt & 1;
    int s0 = kt * 64;
    bool more = (kt + 1 < nkt);
    if (more) { stageK(p ^ 1, kt + 1); vload(kt + 1); }
    if (s0 <= tb + 31) {
      f32x4 accS[2][4];
      for (int mi = 0; mi < 2; mi++) for (int ni = 0; ni < 4; ni++) accS[mi][ni] = fz;
      for (int kk = 0; kk < 2; kk++) {
        int gq = kk * 4 + quad;
        bf16x8 kf[4];
        for (int ni = 0; ni < 4; ni++) { int row = ni * 16 + lq; kf[ni] = *(const bf16x8*)(sK[p] + (row * 8 + (gq ^ (row & 7))) * 8); }
        for (int mi = 0; mi < 2; mi++)
          for (int ni = 0; ni < 4; ni++)
            accS[mi][ni] = __builtin_amdgcn_mfma_f32_16x16x32_bf16(qf[mi][kk], kf[ni], accS[mi][ni], 0, 0, 0);
      }
      for (int mi = 0; mi < 2; mi++) {
        float alpha[4];
        for (int r = 0; r < 4; r++) {
          int trow = tb + mi * 16 + quad * 4 + r;
          float mx = -1e30f;
          for (int ni = 0; ni < 4; ni++) {
            int ss = s0 + ni * 16 + lq;
            float sv = accS[mi][ni][r] * 0.125f;
            sv = (ss > trow) ? -1e30f : sv;
            accS[mi][ni][r] = sv;
            mx = fmaxf(mx, sv);
          }
          for (int d = 1; d < 16; d <<= 1) mx = fmaxf(mx, __shfl_xor(mx, d, 64));
          float mnew = fmaxf(mrow[mi][r], mx);
          float al = __expf(mrow[mi][r] - mnew);
          float rsum = 0.f;
          for (int ni = 0; ni < 4; ni++) {
            float p2 = __expf(accS[mi][ni][r] - mnew);
            accS[mi][ni][r] = p2;
            rsum += p2;
          }
          for (int d = 1; d < 16; d <<= 1) rsum += __shfl_xor(rsum, d, 64);
          lrow[mi][r] = lrow[mi][r] * al + rsum;
          mrow[mi][r] = mnew;
          alpha[r] = al;
        }
        for (int ni = 0; ni < 4; ni++)
          for (int r = 0; r < 4; r++) accO[mi][ni][r] *= alpha[r];
        for (int ni = 0; ni < 4; ni++) {
          int cc = ni * 16 + lq;
          for (int r = 0; r < 4; r++) {
            int row = mi * 16 + quad * 4 + r;
            myP[((cc >> 3) * 32 + row) * 8 + (cc & 7)] = f2bf(accS[mi][ni][r]);
          }
        }
      }
      asm volatile("s_waitcnt lgkmcnt(0)" ::: "memory");
      for (int kk = 0; kk < 2; kk++) {
        int gq = kk * 4 + quad;
        bf16x8 pf[2], vf[4];
        for (int mi = 0; mi < 2; mi++) { int row = mi * 16 + lq; pf[mi] = *(const bf16x8*)(myP + (gq * 32 + row) * 8); }
        for (int ni = 0; ni < 4; ni++) { int row = ni * 16 + lq; vf[ni] = *(const bf16x8*)(sVT[p] + (row * 8 + (gq ^ (row & 7))) * 8); }
        for (int mi = 0; mi < 2; mi++)
          for (int ni = 0; ni < 4; ni++)
            accO[mi][ni] = __builtin_amdgcn_mfma_f32_16x16x32_bf16(pf[mi], vf[ni], accO[mi][ni], 0, 0, 0);
      }
    }
    if (more) {
      vstore(p ^ 1);
      pipe_barrier_full();
    }
  }
  for (int mi = 0; mi < 2; mi++)
    for (int r = 0; r < 4; r++) {
      int trow = tb + mi * 16 + quad * 4 + r;
      float inv = 1.f / lrow[mi][r];
      for (int ni = 0; ni < 4; ni++) {
        int d = ni * 16 + lq;
        y[((size_t)(b * NT + trow)) * NC + h * 64 + d] = f2bf(accO[mi][ni][r] * inv);
      }
    }
}

// ---------------- MoE expert GEMM 1: 512 threads, 128x128 tile (LDS-BW ratio + prologue amortization) ----------------
// waves 2x4: each wave 64 slots x 32 n per gemm. LDS 48KB -> 3 blocks/CU = 24 waves/CU.
__global__ __launch_bounds__(512) void k_moe_e1(const u16t* __restrict__ flat,
                                                const u16t* __restrict__ w1p,
                                                const u16t* __restrict__ w3p,
                                                const int* __restrict__ offs,
                                                const int* __restrict__ tok,
                                                u16t* __restrict__ hh) {
  __shared__ __align__(16) u16t sA[128 * 64];
  __shared__ __align__(16) u16t sB1[128 * 64];
  __shared__ __align__(16) u16t sB3[128 * 64];
  int t = threadIdx.x;
  // 2352 = 8 xcd * 294; 294 = 49 slot-blocks * 6 n-blocks; 392 slot-blocks = 8*49.
  int bid = blockIdx.x;
  int work = (bid & 7) * 294 + (bid >> 3);
  int sb = work / 6;
  int slot0 = sb * 128, n0 = (work - sb * 6) * 128;
  int e = 7;
  for (int i = 0; i < 8; i++) { if (slot0 < offs[i + 1]) { e = i; break; } }
  const u16t* B1 = w1p + (size_t)e * NHIDR * NC;
  const u16t* B3 = w3p + (size_t)e * NHIDR * NC;
  int w = t >> 6, l = t & 63, quad = l >> 4, lq = l & 15;
  int wm = (w >> 2) * 64, wn = (w & 3) * 32;
  const u16t* aP[2]; const u16t* b1P[2]; const u16t* b3P[2];
  for (int i = 0; i < 2; i++) {
    int c = i * 512 + t; int r = c >> 3; int g = (c & 7) ^ (r & 7);
    int tk = tok[slot0 + r]; int row = (tk < 0) ? 0 : tk;
    aP[i] = flat + (size_t)row * NC + g * 8;
    b1P[i] = B1 + (size_t)(n0 + r) * NC + g * 8;   // rows up to 767 -> NHIDR pad
    b3P[i] = B3 + (size_t)(n0 + r) * NC + g * 8;
  }
  const f32x4 fz = {0.f, 0.f, 0.f, 0.f};
  f32x4 a1[4][2], a3[4][2];
  for (int i = 0; i < 4; i++) for (int j = 0; j < 2; j++) { a1[i][j] = fz; a3[i][j] = fz; }
  for (int kb = 0; kb < 4; kb++) {
    int k0 = kb << 6;
    for (int i = 0; i < 2; i++) {
      gload16(aP[i] + k0, sA + (size_t)(i * 512 + t) * 8);
      gload16(b1P[i] + k0, sB1 + (size_t)(i * 512 + t) * 8);
      gload16(b3P[i] + k0, sB3 + (size_t)(i * 512 + t) * 8);
    }
    __syncthreads();
    for (int kk = 0; kk < 2; kk++) {
      int gq = kk * 4 + quad;
      bf16x8 af[4], b1f[2], b3f[2];
      for (int mi = 0; mi < 4; mi++) { int row = wm + mi * 16 + lq; af[mi] = *(const bf16x8*)(sA + (row * 8 + (gq ^ (row & 7))) * 8); }
      for (int ni = 0; ni < 2; ni++) {
        int row = wn + ni * 16 + lq;
        b1f[ni] = *(const bf16x8*)(sB1 + (row * 8 + (gq ^ (row & 7))) * 8);
        b3f[ni] = *(const bf16x8*)(sB3 + (row * 8 + (gq ^ (row & 7))) * 8);
      }
      for (int mi = 0; mi < 4; mi++)
        for (int ni = 0; ni < 2; ni++) {
          a1[mi][ni] = __builtin_amdgcn_mfma_f32_16x16x32_bf16(af[mi], b1f[ni], a1[mi][ni], 0, 0, 0);
          a3[mi][ni] = __builtin_amdgcn_mfma_f32_16x16x32_bf16(af[mi], b3f[ni], a3[mi][ni], 0, 0, 0);
        }
    }
    __syncthreads();
  }
  for (int mi = 0; mi < 4; mi++)
    for (int ni = 0; ni < 2; ni++) {
      int gn = n0 + wn + ni * 16 + lq;
      if (gn < NHIDP) {                     // cols 704-767 are pad-compute, not stored
        for (int r = 0; r < 4; r++) {
          int slot = slot0 + wm + mi * 16 + quad * 4 + r;
          float v1 = a1[mi][ni][r], v3 = a3[mi][ni][r];
          float hv = v1 / (1.f + __expf(-v1)) * v3;
          hh[(size_t)slot * NHIDP + gn] = f2bf(hv);
        }
      }
    }
}

// ---------------- MoE expert GEMM 2 (single-buffer, no setprio): eo[slot] = tokw[slot] * (hh @ w2^T) ----------------
__global__ __launch_bounds__(256) void k_moe_e2(const u16t* __restrict__ hh,
                                                const u16t* __restrict__ w2p,
                                                const int* __restrict__ offs,
                                                const float* __restrict__ tokw,
                                                u16t* __restrict__ eo) {
  __shared__ __align__(16) u16t sA[128 * 64];
  __shared__ __align__(16) u16t sB[128 * 64];
  int t = threadIdx.x;
  // 784 = 8 xcd * 98; 98 = 49 slot-blocks * 2 n-blocks.
  int bid = blockIdx.x;
  int work = (bid & 7) * 98 + (bid >> 3);
  int slot0 = (work >> 1) * 128, n0 = (work & 1) * 128;
  int e = 7;
  for (int i = 0; i < 8; i++) { if (slot0 < offs[i + 1]) { e = i; break; } }
  const u16t* Bw = w2p + (size_t)e * NC * NHIDP;
  int w = t >> 6, l = t & 63, quad = l >> 4, lq = l & 15;
  int wm = (w >> 1) * 64, wn = (w & 1) * 64;
  const u16t* aP[4]; const u16t* bP[4];
  for (int i = 0; i < 4; i++) {
    int c = i * 256 + t; int r = c >> 3; int g = (c & 7) ^ (r & 7);
    aP[i] = hh + (size_t)(slot0 + r) * NHIDP + g * 8;
    bP[i] = Bw + (size_t)(n0 + r) * NHIDP + g * 8;
  }
  const f32x4 fz = {0.f, 0.f, 0.f, 0.f};
  f32x4 acc[4][4];
  for (int i = 0; i < 4; i++) for (int j = 0; j < 4; j++) acc[i][j] = fz;
  for (int kb = 0; kb < 11; kb++) {   // K = 704
    int k0 = kb << 6;
    for (int i = 0; i < 4; i++) {
      gload16(aP[i] + k0, sA + (size_t)(i * 256 + t) * 8);
      gload16(bP[i] + k0, sB + (size_t)(i * 256 + t) * 8);
    }
    __syncthreads();
    for (int kk = 0; kk < 2; kk++) {
      int gq = kk * 4 + quad;
      bf16x8 af[4], bf[4];
      for (int mi = 0; mi < 4; mi++) { int row = wm + mi * 16 + lq; af[mi] = *(const bf16x8*)(sA + (row * 8 + (gq ^ (row & 7))) * 8); }
      for (int ni = 0; ni < 4; ni++) { int row = wn + ni * 16 + lq; bf[ni] = *(const bf16x8*)(sB + (row * 8 + (gq ^ (row & 7))) * 8); }
      for (int mi = 0; mi < 4; mi++)
        for (int ni = 0; ni < 4; ni++)
          acc[mi][ni] = __builtin_amdgcn_mfma_f32_16x16x32_bf16(af[mi], bf[ni], acc[mi][ni], 0, 0, 0);
    }
    __syncthreads();
  }
  for (int mi = 0; mi < 4; mi++)
    for (int r = 0; r < 4; r++) {
      int slot = slot0 + wm + mi * 16 + quad * 4 + r;
      float wgt = tokw[slot];   // 0 for padding slots
      for (int ni = 0; ni < 4; ni++) {
        int gn = n0 + wn + ni * 16 + lq;
        eo[(size_t)slot * NC + gn] = f2bf(wgt * acc[mi][ni][r]);
      }
    }
}

// ---------------- combine: xo[n] += eo[slot0(n)] + eo[slot1(n)] (weighted at e2 store) ----------------
__global__ __launch_bounds__(256) void k_combine(const u16t* __restrict__ eo,
                                                 const int* __restrict__ t2s,
                                                 float* __restrict__ xo) {
  int w = threadIdx.x >> 6, l = threadIdx.x & 63;
  int n = blockIdx.x * 4 + w;
  int g0 = t2s[n * 2], g1 = t2s[n * 2 + 1];
  float* xr = xo + (size_t)n * NC + l * 4;
  float4 xa = *(const float4*)xr;
  ushort4 a = *(const ushort4*)(eo + (size_t)g0 * NC + l * 4);
  ushort4 b = *(const ushort4*)(eo + (size_t)g1 * NC + l * 4);
  xa.x += bf2f(a.x) + bf2f(b.x);
  xa.y += bf2f(a.y) + bf2f(b.y);
  xa.z += bf2f(a.z) + bf2f(b.z);
  xa.w += bf2f(a.w) + bf2f(b.w);
  *(float4*)xr = xa;
}

extern "C" void kernel_launch(void* const* d_in, const int* in_sizes, int n_in,
                              void* d_out, int out_size, void* d_ws, size_t ws_size,
                              hipStream_t stream) {
  (void)in_sizes; (void)n_in; (void)out_size; (void)ws_size;
  const float* x    = (const float*)d_in[0];
  const float* ln1w = (const float*)d_in[1];
  const float* ln2w = (const float*)d_in[2];
  const float* wq   = (const float*)d_in[3];
  const float* wk   = (const float*)d_in[4];
  const float* wv   = (const float*)d_in[5];
  const float* wo   = (const float*)d_in[6];
  const float* rw   = (const float*)d_in[7];
  const float* w1   = (const float*)d_in[8];
  const float* w2   = (const float*)d_in[9];
  const float* w3   = (const float*)d_in[10];
  float* xo = (float*)d_out;   // doubles as x2 residual buffer

  char* ws = (char*)d_ws;
  size_t off = 0;
  int* ctrl  = (int*)(ws + off);  off += 4096;
  int* eidx  = (int*)(ws + off);  off += (size_t)NTOK * 2 * 4;
  float* ew  = (float*)(ws + off); off += (size_t)NTOK * 2 * 4;
  int* tok   = (int*)(ws + off);  off += (size_t)NSLOT * 4;
  float* tokw = (float*)(ws + off); off += (size_t)NSLOT * 4;
  int* t2s   = (int*)(ws + off);  off += (size_t)NTOK * 2 * 4;
  u16t* wqkvb = (u16t*)(ws + off); off += (size_t)512 * 256 * 2;
  u16t* wob  = (u16t*)(ws + off); off += (size_t)256 * 256 * 2;
  u16t* w1p  = (u16t*)(ws + off); off += (size_t)8 * NHIDR * NC * 2;
  u16t* w3p  = (u16t*)(ws + off); off += (size_t)8 * NHIDR * NC * 2;
  u16t* w2p  = (u16t*)(ws + off); off += (size_t)8 * NC * NHIDP * 2;
  float* rtab = (float*)(ws + off); off += (size_t)NT * 32 * 2 * 4;
  u16t* h    = (u16t*)(ws + off); off += (size_t)NTOK * NC * 2;
  u16t* qkv  = (u16t*)(ws + off); off += (size_t)NTOK * 512 * 2;
  u16t* y    = (u16t*)(ws + off); off += (size_t)NTOK * NC * 2;
  u16t* flat = (u16t*)(ws + off); off += (size_t)NTOK * NC * 2;
  u16t* hh   = (u16t*)(ws + off); off += (size_t)NSLOT * NHIDP * 2;
  // eo[NSLOT][256] bf16 (25.7 MB) aliases h+qkv (37.8 MB): both dead after attention,
  // e2/combine run strictly later in the stream.
  u16t* eo   = h;
  int* offs = ctrl + 8;

  k_setup<<<SB6, 256, 0, stream>>>(wq, wk, wv, wo, w1, w2, w3, x, ln1w,
                                   tok, tokw, ctrl, wqkvb, wob, w1p, w3p, w2p, rtab, h);
  k_gemm_qkv<<<dim3(4, NTOK / 128), 256, 0, stream>>>(h, wqkvb, rtab, qkv);
  k_attn<<<dim3(3, 4, NBATCH), 256, 0, stream>>>(qkv, y);
  k_gemm_wo<<<dim3(2, NTOK / 128), 256, 0, stream>>>(y, wob, x, xo);

  k_rms_router<<<NTOK / 4, 256, 0, stream>>>(xo, ln2w, rw, flat, eidx, ew);
  k_hist_scatter<<<NTOK / 256, 256, 0, stream>>>(eidx, ew, ctrl, tok, tokw, t2s);
  k_moe_e1<<<2352, 512, 0, stream>>>(flat, w1p, w3p, offs, tok, hh);
  k_moe_e2<<<784, 256, 0, stream>>>(hh, w2p, offs, tokw, eo);
  k_combine<<<NTOK / 4, 256, 0, stream>>>(eo, t2s, xo);
}

// Round 8
// 290.296 us; speedup vs baseline: 1.0631x; 1.0631x over previous
//
#include <hip/hip_runtime.h>
#include <hip/hip_bf16.h>
#include <math.h>

typedef unsigned short u16t;
typedef __bf16 bf16x8 __attribute__((ext_vector_type(8)));
typedef float f32x4 __attribute__((ext_vector_type(4)));

#define NBATCH 64
#define NT 384
#define NC 256
#define NHID 682
#define NHIDP 704
#define NTOK (NBATCH * NT)          // 24576
#define NSLOT (2 * NTOK + 1024)     // 50176 (128-padded expert regions worst case)

// setup mega-kernel block-range boundaries (256 threads/block)
#define SB0 196                      // init tok/tokw/ctrl        (196*256 = 50176 = NSLOT)
#define SB1 (SB0 + 512)              // wqkv pack   (512*256 = 131072)
#define SB2 (SB1 + 256)              // wo cvt      (256*256 = 65536)
#define SB3 (SB2 + 5632)             // pack13      (8*704*256 = 1441792)
#define SB4 (SB3 + 5632)             // pack2
#define SB5 (SB4 + 48)               // rope table  (384*32 = 12288)
#define SB6 (SB5 + NTOK / 4)         // rms ln1 (4 tokens/block)

static __device__ __forceinline__ float bf2f(u16t u) { return __uint_as_float(((unsigned int)u) << 16); }
static __device__ __forceinline__ u16t f2bf(float f) { return __builtin_bit_cast(u16t, __float2bfloat16(f)); }

// async global->LDS, 16B per lane; LDS dest = wave-uniform base + lane*16.
static __device__ __forceinline__ void gload16(const void* gp, void* lp) {
  __builtin_amdgcn_global_load_lds((const __attribute__((address_space(1))) void*)gp,
                                   (__attribute__((address_space(3))) void*)lp, 16, 0, 0);
}

// pipeline sync helpers: raw barrier with explicit counted waits
static __device__ __forceinline__ void pipe_barrier_full() {
  asm volatile("s_waitcnt vmcnt(0) lgkmcnt(0)" ::: "memory");
  __builtin_amdgcn_s_barrier();
  asm volatile("" ::: "memory");
}

// LDS tile layout: 16B chunks, chunk(row,g) = row*8 + (g ^ (row&7)) (XOR swizzle).

// ---------------- setup mega-kernel: init + weight packs + rope table + ln1 rms ----------------
__global__ __launch_bounds__(256) void k_setup(const float* __restrict__ wq, const float* __restrict__ wk,
                                               const float* __restrict__ wv, const float* __restrict__ wo,
                                               const float* __restrict__ w1, const float* __restrict__ w2,
                                               const float* __restrict__ w3,
                                               const float* __restrict__ x, const float* __restrict__ ln1w,
                                               int* __restrict__ tok, float* __restrict__ tokw,
                                               int* __restrict__ ctrl,
                                               u16t* __restrict__ wqkvb, u16t* __restrict__ wob,
                                               u16t* __restrict__ w1p, u16t* __restrict__ w3p,
                                               u16t* __restrict__ w2p, float* __restrict__ rtab,
                                               u16t* __restrict__ h) {
  int blk = blockIdx.x, t = threadIdx.x;
  if (blk < SB0) {
    int i = blk * 256 + t;
    tok[i] = -1; tokw[i] = 0.f;
    if (blk == 0 && t < 64) ctrl[t] = 0;
  } else if (blk < SB1) {
    int i = (blk - SB0) * 256 + t;
    int row = i >> 8, col = i & 255;
    float s = (row < 256) ? wq[(size_t)row * 256 + col]
            : (row < 384) ? wk[(size_t)(row - 256) * 256 + col]
                          : wv[(size_t)(row - 384) * 256 + col];
    wqkvb[i] = f2bf(s);
  } else if (blk < SB2) {
    int i = (blk - SB1) * 256 + t;
    wob[i] = f2bf(wo[i]);
  } else if (blk < SB3) {
    int idx = (blk - SB2) * 256 + t;
    int kcol = idx & 255; int tmp = idx >> 8; int nrow = tmp % NHIDP; int e = tmp / NHIDP;
    if (nrow < NHID) {
      size_t src = ((size_t)e * NHID + nrow) * NC + kcol;
      w1p[idx] = f2bf(w1[src]); w3p[idx] = f2bf(w3[src]);
    } else { w1p[idx] = 0; w3p[idx] = 0; }
  } else if (blk < SB4) {
    int idx = (blk - SB3) * 256 + t;
    int kcol = idx % NHIDP; int tmp = idx / NHIDP; int nrow = tmp & 255; int e = tmp >> 8;
    w2p[idx] = (kcol < NHID) ? f2bf(w2[((size_t)e * NC + nrow) * NHID + kcol]) : (u16t)0;
  } else if (blk < SB5) {
    int i = (blk - SB4) * 256 + t;   // < 12288
    int tt = i >> 5, d = i & 31;
    float ang = (float)tt * powf(10000.f, -(float)d * (1.f / 32.f));
    float s, c; sincosf(ang, &s, &c);
    ((float2*)rtab)[i] = make_float2(c, s);
  } else {
    int w = t >> 6, l = t & 63;
    int n = (blk - SB5) * 4 + w;
    const float* xr = x + (size_t)n * NC;
    float4 xa = *(const float4*)(xr + l * 4);
    float ssq = xa.x * xa.x + xa.y * xa.y + xa.z * xa.z + xa.w * xa.w;
    for (int d = 1; d < 64; d <<= 1) ssq += __shfl_xor(ssq, d, 64);
    float rs = rsqrtf(ssq * (1.f / 256.f) + 1e-6f);
    float4 wa = *(const float4*)(ln1w + l * 4);
    ushort4 o;
    o.x = f2bf(xa.x * rs * wa.x);
    o.y = f2bf(xa.y * rs * wa.y);
    o.z = f2bf(xa.z * rs * wa.z);
    o.w = f2bf(xa.w * rs * wa.w);
    *(ushort4*)(h + (size_t)n * NC + l * 4) = o;
  }
}

// ---------------- fused RMSNorm + router (fp32), 4 tokens per 256-thr block ----------------
__global__ __launch_bounds__(256) void k_rms_router(const float* __restrict__ xin,
                                                    const float* __restrict__ wg,
                                                    const float* __restrict__ rw,
                                                    u16t* __restrict__ flat,
                                                    int* __restrict__ eidx,
                                                    float* __restrict__ ew) {
  int w = threadIdx.x >> 6, l = threadIdx.x & 63;
  int n = blockIdx.x * 4 + w;
  const float* xr = xin + (size_t)n * NC;
  float4 xa = *(const float4*)(xr + l * 4);
  float ssq = xa.x * xa.x + xa.y * xa.y + xa.z * xa.z + xa.w * xa.w;
  for (int d = 1; d < 64; d <<= 1) ssq += __shfl_xor(ssq, d, 64);
  float rs = rsqrtf(ssq * (1.f / 256.f) + 1e-6f);
  float4 wa = *(const float4*)(wg + l * 4);
  float n0 = xa.x * rs * wa.x, n1 = xa.y * rs * wa.y;
  float n2 = xa.z * rs * wa.z, n3 = xa.w * rs * wa.w;
  ushort4 o; o.x = f2bf(n0); o.y = f2bf(n1); o.z = f2bf(n2); o.w = f2bf(n3);
  *(ushort4*)(flat + (size_t)n * NC + l * 4) = o;
  float acc[8];
  for (int e = 0; e < 8; e++) {
    float4 ra = *(const float4*)(rw + (size_t)e * NC + l * 4);
    acc[e] = n0 * ra.x + n1 * ra.y + n2 * ra.z + n3 * ra.w;
  }
  for (int e = 0; e < 8; e++)
    for (int d = 1; d < 64; d <<= 1) acc[e] += __shfl_xor(acc[e], d, 64);
  if (l == 0) {
    float mx = acc[0];
    for (int e = 1; e < 8; e++) mx = fmaxf(mx, acc[e]);
    float p[8], sum = 0.f;
    for (int e = 0; e < 8; e++) { p[e] = __expf(acc[e] - mx); sum += p[e]; }
    float inv = 1.f / sum;
    for (int e = 0; e < 8; e++) p[e] *= inv;
    int i0 = 0; float b0 = p[0];
    for (int e = 1; e < 8; e++) if (p[e] > b0) { b0 = p[e]; i0 = e; }
    int i1 = -1; float b1 = -1.f;
    for (int e = 0; e < 8; e++) if (e != i0 && p[e] > b1) { b1 = p[e]; i1 = e; }
    float s2 = 1.f / (b0 + b1 + 1e-9f);
    eidx[n * 2] = i0; eidx[n * 2 + 1] = i1;
    ew[n * 2] = b0 * s2; ew[n * 2 + 1] = b1 * s2;
  }
}

// ---------------- expert-count histogram + inline scan (last block) ----------------
__global__ __launch_bounds__(256) void k_hist(const int* __restrict__ eidx, int* __restrict__ ctrl) {
  int* cnt = ctrl; int* offs = ctrl + 8; int* cursor = ctrl + 20; int* done = ctrl + 32;
  __shared__ int lh[8];
  if (threadIdx.x < 8) lh[threadIdx.x] = 0;
  __syncthreads();
  int base = blockIdx.x * 1024 + threadIdx.x;
  for (int i = 0; i < 4; i++) atomicAdd(&lh[eidx[base + i * 256]], 1);
  __syncthreads();
  if (threadIdx.x < 8) {
    atomicAdd(&cnt[threadIdx.x], lh[threadIdx.x]);
    __threadfence();
  }
  __syncthreads();
  if (threadIdx.x == 0) {
    int prev = atomicAdd(done, 1);
    if (prev == 47) {   // last block: all cnt updates visible
      int off = 0;
      for (int e = 0; e < 8; e++) {
        int c_ = atomicAdd(&cnt[e], 0);
        offs[e] = off; cursor[e] = off;
        off += ((c_ + 127) >> 7) << 7;
      }
      offs[8] = off;
    }
  }
}

// ---------------- fused QKV GEMM + RoPE epilogue (2-phase pipelined) ----------------
// qkv[N][512]: cols 0-255 q (4 heads), 256-383 k (2 kv heads), 384-511 v.
// NOTE: natural dim3 grid. XCD-chunked flat grid was measured -12 us across qkv/attn/wo (R5):
// all operands are L3-resident here, so L2-locality swizzling only perturbs dispatch balance.
__global__ __launch_bounds__(256) void k_gemm_qkv(const u16t* __restrict__ A,
                                                  const u16t* __restrict__ Bw,
                                                  const float* __restrict__ rtab,
                                                  u16t* __restrict__ qkv) {
  __shared__ __align__(16) u16t sA[2][128 * 64];
  __shared__ __align__(16) u16t sB[2][128 * 64];
  int t = threadIdx.x;
  int m0 = blockIdx.y * 128, n0 = blockIdx.x * 128;
  int w = t >> 6, l = t & 63, quad = l >> 4, lq = l & 15;
  int wm = (w >> 1) * 64, wn = (w & 1) * 64;
  const u16t* aP[4]; const u16t* bP[4];
  for (int i = 0; i < 4; i++) {
    int c = i * 256 + t; int r = c >> 3; int g = (c & 7) ^ (r & 7);
    aP[i] = A + (size_t)(m0 + r) * NC + g * 8;
    bP[i] = Bw + (size_t)(n0 + r) * NC + g * 8;
  }
  auto stage = [&](int p, int k0) {
    for (int i = 0; i < 4; i++) {
      gload16(aP[i] + k0, sA[p] + (size_t)(i * 256 + t) * 8);
      gload16(bP[i] + k0, sB[p] + (size_t)(i * 256 + t) * 8);
    }
  };
  const f32x4 fz = {0.f, 0.f, 0.f, 0.f};
  f32x4 acc[4][4];
  for (int i = 0; i < 4; i++) for (int j = 0; j < 4; j++) acc[i][j] = fz;
  stage(0, 0);
  pipe_barrier_full();
  for (int kb = 0; kb < 4; kb++) {
    int p = kb & 1;
    if (kb < 3) stage(p ^ 1, (kb + 1) << 6);
    for (int kk = 0; kk < 2; kk++) {
      int gq = kk * 4 + quad;
      bf16x8 af[4], bf[4];
      for (int mi = 0; mi < 4; mi++) { int row = wm + mi * 16 + lq; af[mi] = *(const bf16x8*)(sA[p] + (row * 8 + (gq ^ (row & 7))) * 8); }
      for (int ni = 0; ni < 4; ni++) { int row = wn + ni * 16 + lq; bf[ni] = *(const bf16x8*)(sB[p] + (row * 8 + (gq ^ (row & 7))) * 8); }
      for (int mi = 0; mi < 4; mi++)
        for (int ni = 0; ni < 4; ni++)
          acc[mi][ni] = __builtin_amdgcn_mfma_f32_16x16x32_bf16(af[mi], bf[ni], acc[mi][ni], 0, 0, 0);
    }
    if (kb < 3) pipe_barrier_full();
  }
  int cb = (n0 + wn) >> 6;                // 64-col head block owned by this wave
  const float2* rt = (const float2*)rtab;
  for (int mi = 0; mi < 4; mi++)
    for (int r = 0; r < 4; r++) {
      int gm = m0 + wm + mi * 16 + quad * 4 + r;
      u16t* orow = qkv + (size_t)gm * 512 + n0 + wn;
      if (cb < 6) {                       // q or k head: rope pairs (d, d+32)
        int tt = gm % NT;
        for (int ni = 0; ni < 2; ni++) {
          int d = ni * 16 + lq;
          float2 cs = rt[tt * 32 + d];
          float x1 = acc[mi][ni][r], x2 = acc[mi][ni + 2][r];
          orow[d] = f2bf(x1 * cs.x - x2 * cs.y);
          orow[d + 32] = f2bf(x2 * cs.x + x1 * cs.y);
        }
      } else {                            // v: plain store
        for (int ni = 0; ni < 4; ni++) orow[ni * 16 + lq] = f2bf(acc[mi][ni][r]);
      }
    }
}

// ---------------- GEMM + residual: xo_f32 = y @ wo^T + x_f32 (2-phase pipelined) ----------------
__global__ __launch_bounds__(256) void k_gemm_wo(const u16t* __restrict__ A,
                                                 const u16t* __restrict__ Bw,
                                                 const float* __restrict__ xin,
                                                 float* __restrict__ xo) {
  __shared__ __align__(16) u16t sA[2][128 * 64];
  __shared__ __align__(16) u16t sB[2][128 * 64];
  int t = threadIdx.x;
  int m0 = blockIdx.y * 128, n0 = blockIdx.x * 128;
  int w = t >> 6, l = t & 63, quad = l >> 4, lq = l & 15;
  int wm = (w >> 1) * 64, wn = (w & 1) * 64;
  const u16t* aP[4]; const u16t* bP[4];
  for (int i = 0; i < 4; i++) {
    int c = i * 256 + t; int r = c >> 3; int g = (c & 7) ^ (r & 7);
    aP[i] = A + (size_t)(m0 + r) * NC + g * 8;
    bP[i] = Bw + (size_t)(n0 + r) * NC + g * 8;
  }
  auto stage = [&](int p, int k0) {
    for (int i = 0; i < 4; i++) {
      gload16(aP[i] + k0, sA[p] + (size_t)(i * 256 + t) * 8);
      gload16(bP[i] + k0, sB[p] + (size_t)(i * 256 + t) * 8);
    }
  };
  const f32x4 fz = {0.f, 0.f, 0.f, 0.f};
  f32x4 acc[4][4];
  for (int i = 0; i < 4; i++) for (int j = 0; j < 4; j++) acc[i][j] = fz;
  stage(0, 0);
  pipe_barrier_full();
  for (int kb = 0; kb < 4; kb++) {
    int p = kb & 1;
    if (kb < 3) stage(p ^ 1, (kb + 1) << 6);
    for (int kk = 0; kk < 2; kk++) {
      int gq = kk * 4 + quad;
      bf16x8 af[4], bf[4];
      for (int mi = 0; mi < 4; mi++) { int row = wm + mi * 16 + lq; af[mi] = *(const bf16x8*)(sA[p] + (row * 8 + (gq ^ (row & 7))) * 8); }
      for (int ni = 0; ni < 4; ni++) { int row = wn + ni * 16 + lq; bf[ni] = *(const bf16x8*)(sB[p] + (row * 8 + (gq ^ (row & 7))) * 8); }
      for (int mi = 0; mi < 4; mi++)
        for (int ni = 0; ni < 4; ni++)
          acc[mi][ni] = __builtin_amdgcn_mfma_f32_16x16x32_bf16(af[mi], bf[ni], acc[mi][ni], 0, 0, 0);
    }
    if (kb < 3) pipe_barrier_full();
  }
  for (int mi = 0; mi < 4; mi++)
    for (int ni = 0; ni < 4; ni++) {
      int gn = n0 + wn + ni * 16 + lq;
      for (int r = 0; r < 4; r++) {
        int gm = m0 + wm + mi * 16 + quad * 4 + r;
        xo[(size_t)gm * NC + gn] = acc[mi][ni][r] + xin[(size_t)gm * NC + gn];
      }
    }
}

// ---------------- flash attention, causal GQA (bf16), 2-phase K/V pipeline ----------------
__global__ __launch_bounds__(256) void k_attn(const u16t* __restrict__ qkv,
                                              u16t* __restrict__ y) {
  __shared__ __align__(16) u16t sK[2][64 * 64];
  __shared__ __align__(16) u16t sVT[2][64 * 64];
  __shared__ __align__(16) u16t sP[4 * 32 * 64];
  int qt = blockIdx.x, h = blockIdx.y, b = blockIdx.z;
  int kvh = h >> 1;
  int t = threadIdx.x, w = t >> 6, l = t & 63, quad = l >> 4, lq = l & 15;
  int tb = qt * 128 + w * 32;
  bf16x8 qf[2][2];
  for (int mi = 0; mi < 2; mi++)
    for (int kk = 0; kk < 2; kk++)
      qf[mi][kk] = *(const bf16x8*)(qkv + ((size_t)(b * NT + tb + mi * 16 + lq)) * 512 + h * 64 + kk * 32 + quad * 8);
  const f32x4 fz = {0.f, 0.f, 0.f, 0.f};
  f32x4 accO[2][4];
  float mrow[2][4], lrow[2][4];
  for (int mi = 0; mi < 2; mi++)
    for (int ni = 0; ni < 4; ni++) accO[mi][ni] = fz;
  for (int mi = 0; mi < 2; mi++)
    for (int r = 0; r < 4; r++) { mrow[mi][r] = -1e30f; lrow[mi][r] = 0.f; }
  u16t* myP = sP + w * 2048;
  int nkt = (qt + 1) * 2;
  ushort4 vr0[2], vr1[2];
  auto stageK = [&](int p, int kt) {
    int s0 = kt * 64;
    for (int i = 0; i < 2; i++) {
      int c = i * 256 + t; int s = c >> 3; int g = (c & 7) ^ (s & 7);
      gload16(qkv + ((size_t)(b * NT + s0 + s)) * 512 + 256 + kvh * 64 + g * 8, sK[p] + (size_t)c * 8);
    }
  };
  auto vload = [&](int kt) {                 // issue V global loads into regs (T14 issue-early)
    int s0 = kt * 64;
    for (int i = 0; i < 2; i++) {
      int pI = i * 256 + t; int s = pI & 63; int n0 = (pI >> 6) * 8;
      const u16t* vp = qkv + ((size_t)(b * NT + s0 + s)) * 512 + 384 + kvh * 64 + n0;
      vr0[i] = *(const ushort4*)vp; vr1[i] = *(const ushort4*)(vp + 4);
    }
  };
  auto vstore = [&](int p) {                 // transpose-write V into LDS (T14 write-late)
    for (int i = 0; i < 2; i++) {
      int pI = i * 256 + t; int s = pI & 63; int n0 = (pI >> 6) * 8;
      u16t vv[8] = {vr0[i].x, vr0[i].y, vr0[i].z, vr0[i].w, vr1[i].x, vr1[i].y, vr1[i].z, vr1[i].w};
      for (int j = 0; j < 8; j++) {
        int nn = n0 + j;
        sVT[p][(nn * 8 + ((s >> 3) ^ (nn & 7))) * 8 + (s & 7)] = vv[j];
      }
    }
  };
  stageK(0, 0); vload(0); vstore(0);
  pipe_barrier_full();
  for (int kt = 0; kt < nkt; kt++) {
    int p = kt & 1;
    int s0 = kt * 64;
    bool more = (kt + 1 < nkt);
    if (more) { stageK(p ^ 1, kt + 1); vload(kt + 1); }
    if (s0 <= tb + 31) {
      f32x4 accS[2][4];
      for (int mi = 0; mi < 2; mi++) for (int ni = 0; ni < 4; ni++) accS[mi][ni] = fz;
      for (int kk = 0; kk < 2; kk++) {
        int gq = kk * 4 + quad;
        bf16x8 kf[4];
        for (int ni = 0; ni < 4; ni++) { int row = ni * 16 + lq; kf[ni] = *(const bf16x8*)(sK[p] + (row * 8 + (gq ^ (row & 7))) * 8); }
        for (int mi = 0; mi < 2; mi++)
          for (int ni = 0; ni < 4; ni++)
            accS[mi][ni] = __builtin_amdgcn_mfma_f32_16x16x32_bf16(qf[mi][kk], kf[ni], accS[mi][ni], 0, 0, 0);
      }
      for (int mi = 0; mi < 2; mi++) {
        float alpha[4];
        for (int r = 0; r < 4; r++) {
          int trow = tb + mi * 16 + quad * 4 + r;
          float mx = -1e30f;
          for (int ni = 0; ni < 4; ni++) {
            int ss = s0 + ni * 16 + lq;
            float sv = accS[mi][ni][r] * 0.125f;
            sv = (ss > trow) ? -1e30f : sv;
            accS[mi][ni][r] = sv;
            mx = fmaxf(mx, sv);
          }
          for (int d = 1; d < 16; d <<= 1) mx = fmaxf(mx, __shfl_xor(mx, d, 64));
          float mnew = fmaxf(mrow[mi][r], mx);
          float al = __expf(mrow[mi][r] - mnew);
          float rsum = 0.f;
          for (int ni = 0; ni < 4; ni++) {
            float p2 = __expf(accS[mi][ni][r] - mnew);
            accS[mi][ni][r] = p2;
            rsum += p2;
          }
          for (int d = 1; d < 16; d <<= 1) rsum += __shfl_xor(rsum, d, 64);
          lrow[mi][r] = lrow[mi][r] * al + rsum;
          mrow[mi][r] = mnew;
          alpha[r] = al;
        }
        for (int ni = 0; ni < 4; ni++)
          for (int r = 0; r < 4; r++) accO[mi][ni][r] *= alpha[r];
        for (int ni = 0; ni < 4; ni++) {
          int cc = ni * 16 + lq;
          for (int r = 0; r < 4; r++) {
            int row = mi * 16 + quad * 4 + r;
            myP[((cc >> 3) * 32 + row) * 8 + (cc & 7)] = f2bf(accS[mi][ni][r]);
          }
        }
      }
      asm volatile("s_waitcnt lgkmcnt(0)" ::: "memory");
      for (int kk = 0; kk < 2; kk++) {
        int gq = kk * 4 + quad;
        bf16x8 pf[2], vf[4];
        for (int mi = 0; mi < 2; mi++) { int row = mi * 16 + lq; pf[mi] = *(const bf16x8*)(myP + (gq * 32 + row) * 8); }
        for (int ni = 0; ni < 4; ni++) { int row = ni * 16 + lq; vf[ni] = *(const bf16x8*)(sVT[p] + (row * 8 + (gq ^ (row & 7))) * 8); }
        for (int mi = 0; mi < 2; mi++)
          for (int ni = 0; ni < 4; ni++)
            accO[mi][ni] = __builtin_amdgcn_mfma_f32_16x16x32_bf16(pf[mi], vf[ni], accO[mi][ni], 0, 0, 0);
      }
    }
    if (more) {
      vstore(p ^ 1);
      pipe_barrier_full();
    }
  }
  for (int mi = 0; mi < 2; mi++)
    for (int r = 0; r < 4; r++) {
      int trow = tb + mi * 16 + quad * 4 + r;
      float inv = 1.f / lrow[mi][r];
      for (int ni = 0; ni < 4; ni++) {
        int d = ni * 16 + lq;
        y[((size_t)(b * NT + trow)) * NC + h * 64 + d] = f2bf(accO[mi][ni][r] * inv);
      }
    }
}

// ---------------- block-aggregated scatter: 8 reservation atomics per block ----------------
__global__ __launch_bounds__(256) void k_scatter(const int* __restrict__ eidx, const float* __restrict__ ew,
                                                 int* __restrict__ cursor, int* __restrict__ tok,
                                                 float* __restrict__ tokw, int* __restrict__ t2s) {
  __shared__ int lcnt[8], lbase[8];
  if (threadIdx.x < 8) lcnt[threadIdx.x] = 0;
  __syncthreads();
  int n = blockIdx.x * 256 + threadIdx.x;
  int e0 = eidx[n * 2], e1 = eidx[n * 2 + 1];
  int p0 = atomicAdd(&lcnt[e0], 1);
  int p1 = atomicAdd(&lcnt[e1], 1);
  __syncthreads();
  if (threadIdx.x < 8) lbase[threadIdx.x] = atomicAdd(&cursor[threadIdx.x], lcnt[threadIdx.x]);
  __syncthreads();
  int g0 = lbase[e0] + p0, g1 = lbase[e1] + p1;
  tok[g0] = n; tokw[g0] = ew[n * 2];
  tok[g1] = n; tokw[g1] = ew[n * 2 + 1];
  t2s[n * 2] = g0; t2s[n * 2 + 1] = g1;
}

// ---------------- MoE expert GEMM 1 (single-buffer, 32KB LDS — measured best config) ----------------
__global__ __launch_bounds__(256) void k_moe_e1(const u16t* __restrict__ flat,
                                                const u16t* __restrict__ w1p,
                                                const u16t* __restrict__ w3p,
                                                const int* __restrict__ offs,
                                                const int* __restrict__ tok,
                                                u16t* __restrict__ hh) {
  __shared__ __align__(16) u16t sA[128 * 64];
  __shared__ __align__(16) u16t sB1[64 * 64];
  __shared__ __align__(16) u16t sB3[64 * 64];
  int t = threadIdx.x;
  // 4312 = 8 xcd * 539; 539 = 49 slot-blocks * 11 n-blocks; 392 slot-blocks = 8*49.
  int bid = blockIdx.x;
  int work = (bid & 7) * 539 + (bid >> 3);
  int sb = work / 11;
  int slot0 = sb * 128, n0 = (work - sb * 11) * 64;
  int e = 7;
  for (int i = 0; i < 8; i++) { if (slot0 < offs[i + 1]) { e = i; break; } }
  const u16t* B1 = w1p + (size_t)e * NHIDP * NC;
  const u16t* B3 = w3p + (size_t)e * NHIDP * NC;
  int w = t >> 6, l = t & 63, quad = l >> 4, lq = l & 15;
  int wm = (w >> 1) * 64, wn = (w & 1) * 32;
  const u16t* aP[4]; const u16t* b1P[2]; const u16t* b3P[2];
  for (int i = 0; i < 4; i++) {
    int c = i * 256 + t; int r = c >> 3; int g = (c & 7) ^ (r & 7);
    int tk = tok[slot0 + r]; int row = (tk < 0) ? 0 : tk;
    aP[i] = flat + (size_t)row * NC + g * 8;
  }
  for (int i = 0; i < 2; i++) {
    int c = i * 256 + t; int r = c >> 3; int g = (c & 7) ^ (r & 7);
    b1P[i] = B1 + (size_t)(n0 + r) * NC + g * 8;
    b3P[i] = B3 + (size_t)(n0 + r) * NC + g * 8;
  }
  const f32x4 fz = {0.f, 0.f, 0.f, 0.f};
  f32x4 a1[4][2], a3[4][2];
  for (int i = 0; i < 4; i++) for (int j = 0; j < 2; j++) { a1[i][j] = fz; a3[i][j] = fz; }
  for (int kb = 0; kb < 4; kb++) {
    int k0 = kb << 6;
    for (int i = 0; i < 4; i++)
      gload16(aP[i] + k0, sA + (size_t)(i * 256 + t) * 8);
    for (int i = 0; i < 2; i++) {
      gload16(b1P[i] + k0, sB1 + (size_t)(i * 256 + t) * 8);
      gload16(b3P[i] + k0, sB3 + (size_t)(i * 256 + t) * 8);
    }
    __syncthreads();
    for (int kk = 0; kk < 2; kk++) {
      int gq = kk * 4 + quad;
      bf16x8 af[4], b1f[2], b3f[2];
      for (int mi = 0; mi < 4; mi++) { int row = wm + mi * 16 + lq; af[mi] = *(const bf16x8*)(sA + (row * 8 + (gq ^ (row & 7))) * 8); }
      for (int ni = 0; ni < 2; ni++) {
        int row = wn + ni * 16 + lq;
        b1f[ni] = *(const bf16x8*)(sB1 + (row * 8 + (gq ^ (row & 7))) * 8);
        b3f[ni] = *(const bf16x8*)(sB3 + (row * 8 + (gq ^ (row & 7))) * 8);
      }
      for (int mi = 0; mi < 4; mi++)
        for (int ni = 0; ni < 2; ni++) {
          a1[mi][ni] = __builtin_amdgcn_mfma_f32_16x16x32_bf16(af[mi], b1f[ni], a1[mi][ni], 0, 0, 0);
          a3[mi][ni] = __builtin_amdgcn_mfma_f32_16x16x32_bf16(af[mi], b3f[ni], a3[mi][ni], 0, 0, 0);
        }
    }
    __syncthreads();
  }
  for (int mi = 0; mi < 4; mi++)
    for (int ni = 0; ni < 2; ni++) {
      int gn = n0 + wn + ni * 16 + lq;
      for (int r = 0; r < 4; r++) {
        int slot = slot0 + wm + mi * 16 + quad * 4 + r;
        float v1 = a1[mi][ni][r], v3 = a3[mi][ni][r];
        float hv = v1 / (1.f + __expf(-v1)) * v3;
        hh[(size_t)slot * NHIDP + gn] = f2bf(hv);
      }
    }
}

// ---------------- MoE expert GEMM 2 (2-phase pipelined, 11 K-steps amortize prologue) ----------------
__global__ __launch_bounds__(256) void k_moe_e2(const u16t* __restrict__ hh,
                                                const u16t* __restrict__ w2p,
                                                const int* __restrict__ offs,
                                                const float* __restrict__ tokw,
                                                u16t* __restrict__ eo) {
  __shared__ __align__(16) u16t sA[2][128 * 64];
  __shared__ __align__(16) u16t sB[2][128 * 64];
  int t = threadIdx.x;
  // 784 = 8 xcd * 98; 98 = 49 slot-blocks * 2 n-blocks.
  int bid = blockIdx.x;
  int work = (bid & 7) * 98 + (bid >> 3);
  int slot0 = (work >> 1) * 128, n0 = (work & 1) * 128;
  int e = 7;
  for (int i = 0; i < 8; i++) { if (slot0 < offs[i + 1]) { e = i; break; } }
  const u16t* Bw = w2p + (size_t)e * NC * NHIDP;
  int w = t >> 6, l = t & 63, quad = l >> 4, lq = l & 15;
  int wm = (w >> 1) * 64, wn = (w & 1) * 64;
  const u16t* aP[4]; const u16t* bP[4];
  for (int i = 0; i < 4; i++) {
    int c = i * 256 + t; int r = c >> 3; int g = (c & 7) ^ (r & 7);
    aP[i] = hh + (size_t)(slot0 + r) * NHIDP + g * 8;
    bP[i] = Bw + (size_t)(n0 + r) * NHIDP + g * 8;
  }
  auto stage = [&](int p, int k0) {
    for (int i = 0; i < 4; i++) {
      gload16(aP[i] + k0, sA[p] + (size_t)(i * 256 + t) * 8);
      gload16(bP[i] + k0, sB[p] + (size_t)(i * 256 + t) * 8);
    }
  };
  const f32x4 fz = {0.f, 0.f, 0.f, 0.f};
  f32x4 acc[4][4];
  for (int i = 0; i < 4; i++) for (int j = 0; j < 4; j++) acc[i][j] = fz;
  stage(0, 0);
  pipe_barrier_full();
  for (int kb = 0; kb < 11; kb++) {   // K = 704
    int p = kb & 1;
    if (kb < 10) stage(p ^ 1, (kb + 1) << 6);
    for (int kk = 0; kk < 2; kk++) {
      int gq = kk * 4 + quad;
      bf16x8 af[4], bf[4];
      for (int mi = 0; mi < 4; mi++) { int row = wm + mi * 16 + lq; af[mi] = *(const bf16x8*)(sA[p] + (row * 8 + (gq ^ (row & 7))) * 8); }
      for (int ni = 0; ni < 4; ni++) { int row = wn + ni * 16 + lq; bf[ni] = *(const bf16x8*)(sB[p] + (row * 8 + (gq ^ (row & 7))) * 8); }
      for (int mi = 0; mi < 4; mi++)
        for (int ni = 0; ni < 4; ni++)
          acc[mi][ni] = __builtin_amdgcn_mfma_f32_16x16x32_bf16(af[mi], bf[ni], acc[mi][ni], 0, 0, 0);
    }
    if (kb < 10) pipe_barrier_full();
  }
  for (int mi = 0; mi < 4; mi++)
    for (int r = 0; r < 4; r++) {
      int slot = slot0 + wm + mi * 16 + quad * 4 + r;
      float wgt = tokw[slot];   // 0 for padding slots
      for (int ni = 0; ni < 4; ni++) {
        int gn = n0 + wn + ni * 16 + lq;
        eo[(size_t)slot * NC + gn] = f2bf(wgt * acc[mi][ni][r]);
      }
    }
}

// ---------------- combine: xo[n] += eo[slot0(n)] + eo[slot1(n)] (weighted at e2 store) ----------------
__global__ __launch_bounds__(256) void k_combine(const u16t* __restrict__ eo,
                                                 const int* __restrict__ t2s,
                                                 float* __restrict__ xo) {
  int w = threadIdx.x >> 6, l = threadIdx.x & 63;
  int n = blockIdx.x * 4 + w;
  int g0 = t2s[n * 2], g1 = t2s[n * 2 + 1];
  float* xr = xo + (size_t)n * NC + l * 4;
  float4 xa = *(const float4*)xr;
  ushort4 a = *(const ushort4*)(eo + (size_t)g0 * NC + l * 4);
  ushort4 b = *(const ushort4*)(eo + (size_t)g1 * NC + l * 4);
  xa.x += bf2f(a.x) + bf2f(b.x);
  xa.y += bf2f(a.y) + bf2f(b.y);
  xa.z += bf2f(a.z) + bf2f(b.z);
  xa.w += bf2f(a.w) + bf2f(b.w);
  *(float4*)xr = xa;
}

extern "C" void kernel_launch(void* const* d_in, const int* in_sizes, int n_in,
                              void* d_out, int out_size, void* d_ws, size_t ws_size,
                              hipStream_t stream) {
  (void)in_sizes; (void)n_in; (void)out_size; (void)ws_size;
  const float* x    = (const float*)d_in[0];
  const float* ln1w = (const float*)d_in[1];
  const float* ln2w = (const float*)d_in[2];
  const float* wq   = (const float*)d_in[3];
  const float* wk   = (const float*)d_in[4];
  const float* wv   = (const float*)d_in[5];
  const float* wo   = (const float*)d_in[6];
  const float* rw   = (const float*)d_in[7];
  const float* w1   = (const float*)d_in[8];
  const float* w2   = (const float*)d_in[9];
  const float* w3   = (const float*)d_in[10];
  float* xo = (float*)d_out;   // doubles as x2 residual buffer

  char* ws = (char*)d_ws;
  size_t off = 0;
  int* ctrl  = (int*)(ws + off);  off += 4096;
  int* eidx  = (int*)(ws + off);  off += (size_t)NTOK * 2 * 4;
  float* ew  = (float*)(ws + off); off += (size_t)NTOK * 2 * 4;
  int* tok   = (int*)(ws + off);  off += (size_t)NSLOT * 4;
  float* tokw = (float*)(ws + off); off += (size_t)NSLOT * 4;
  int* t2s   = (int*)(ws + off);  off += (size_t)NTOK * 2 * 4;
  u16t* wqkvb = (u16t*)(ws + off); off += (size_t)512 * 256 * 2;
  u16t* wob  = (u16t*)(ws + off); off += (size_t)256 * 256 * 2;
  u16t* w1p  = (u16t*)(ws + off); off += (size_t)8 * NHIDP * NC * 2;
  u16t* w3p  = (u16t*)(ws + off); off += (size_t)8 * NHIDP * NC * 2;
  u16t* w2p  = (u16t*)(ws + off); off += (size_t)8 * NC * NHIDP * 2;
  float* rtab = (float*)(ws + off); off += (size_t)NT * 32 * 2 * 4;
  u16t* h    = (u16t*)(ws + off); off += (size_t)NTOK * NC * 2;
  u16t* qkv  = (u16t*)(ws + off); off += (size_t)NTOK * 512 * 2;
  u16t* y    = (u16t*)(ws + off); off += (size_t)NTOK * NC * 2;
  u16t* flat = (u16t*)(ws + off); off += (size_t)NTOK * NC * 2;
  u16t* hh   = (u16t*)(ws + off); off += (size_t)NSLOT * NHIDP * 2;
  // eo[NSLOT][256] bf16 (25.7 MB) aliases h+qkv (37.8 MB): both dead after attention,
  // e2/combine run strictly later in the stream.
  u16t* eo   = h;
  int* offs = ctrl + 8; int* cursor = ctrl + 20;

  k_setup<<<SB6, 256, 0, stream>>>(wq, wk, wv, wo, w1, w2, w3, x, ln1w,
                                   tok, tokw, ctrl, wqkvb, wob, w1p, w3p, w2p, rtab, h);
  k_gemm_qkv<<<dim3(4, NTOK / 128), 256, 0, stream>>>(h, wqkvb, rtab, qkv);
  k_attn<<<dim3(3, 4, NBATCH), 256, 0, stream>>>(qkv, y);
  k_gemm_wo<<<dim3(2, NTOK / 128), 256, 0, stream>>>(y, wob, x, xo);

  k_rms_router<<<NTOK / 4, 256, 0, stream>>>(xo, ln2w, rw, flat, eidx, ew);
  k_hist<<<48, 256, 0, stream>>>(eidx, ctrl);
  k_scatter<<<NTOK / 256, 256, 0, stream>>>(eidx, ew, cursor, tok, tokw, t2s);
  k_moe_e1<<<4312, 256, 0, stream>>>(flat, w1p, w3p, offs, tok, hh);
  k_moe_e2<<<784, 256, 0, stream>>>(hh, w2p, offs, tokw, eo);
  k_combine<<<NTOK / 4, 256, 0, stream>>>(eo, t2s, xo);
}